// Round 6
// baseline (3918.681 us; speedup 1.0000x reference)
//
#include <hip/hip_runtime.h>
#include <math.h>

typedef __attribute__((ext_vector_type(8))) short bf16x8;
typedef __attribute__((ext_vector_type(4))) float f32x4;

#define DEVI static __device__ __forceinline__

// Problem constants
#define BB 256
#define TT 128
#define II 256
#define HH 512
#define GG 2048   // 4*H
#define OUT_HN (256*128*512)                 // 16777216
#define OUT_CN (OUT_HN + 256*2*512)          // 17039360

DEVI unsigned short f2bf(float f) {
  unsigned u = __float_as_uint(f);
  u += 0x7FFFu + ((u >> 16) & 1u);   // round-to-nearest-even
  return (unsigned short)(u >> 16);
}
DEVI float bf2f(unsigned short h) { return __uint_as_float(((unsigned)h) << 16); }
DEVI float sigm(float x) { return 1.0f / (1.0f + __expf(-x)); }

// ---------------- prep kernels ----------------

__global__ void detect_init_kernel(const unsigned int* w, int nwords, int* flag) {
  __shared__ int sawFloat, sawBig;
  if (threadIdx.x == 0) { sawFloat = 0; sawBig = 0; }
  __syncthreads();
  int lf = 0, lb = 0;
  for (int i = threadIdx.x; i < nwords; i += blockDim.x) {
    unsigned v = w[i];
    if (v == 0x3F800000u) lf = 1;
    else if (v > 1u) lb = 1;
  }
  if (lf) atomicOr(&sawFloat, 1);
  if (lb) atomicOr(&sawBig, 1);
  __syncthreads();
  if (threadIdx.x == 0) *flag = sawFloat ? 2 : (sawBig ? 1 : 0);
}

__global__ void expand_mask_kernel(const void* is_init, const int* flag,
                                   unsigned char* mask, int n) {
  int i = blockIdx.x * blockDim.x + threadIdx.x;
  if (i >= n) return;
  int mode = *flag;
  int v;
  if (mode == 2)      v = ((const unsigned int*)is_init)[i] != 0u;
  else if (mode == 1) v = ((const unsigned char*)is_init)[i] != 0;
  else                v = ((const int*)is_init)[i] != 0;
  mask[i] = (unsigned char)v;
}

__global__ void conv_bf16_kernel(const float* __restrict__ src,
                                 unsigned short* __restrict__ dst, int n) {
  for (int i = blockIdx.x * blockDim.x + threadIdx.x; i < n; i += gridDim.x * blockDim.x)
    dst[i] = f2bf(src[i]);
}

// W1cat[n][k]: k<512 -> W_ih1[n][k]; k>=512 -> W_hh1[n][k-512]   (2048 x 1024 bf16)
__global__ void build_w1cat_kernel(const float* __restrict__ wih1,
                                   const float* __restrict__ whh1,
                                   unsigned short* __restrict__ dst) {
  const int total = GG * 1024;
  for (int i = blockIdx.x * blockDim.x + threadIdx.x; i < total; i += gridDim.x * blockDim.x) {
    int n = i >> 10, k = i & 1023;
    float v = (k < 512) ? wih1[n * 512 + k] : whh1[n * 512 + (k - 512)];
    dst[i] = f2bf(v);
  }
}

__global__ void build_bias_kernel(const float* __restrict__ ba,
                                  const float* __restrict__ bb,
                                  float* __restrict__ dst) {
  int i = blockIdx.x * blockDim.x + threadIdx.x;
  if (i < GG) dst[i] = ba[i] + bb[i];
}

// initial states: h (B,2,H) -> bf16 parity-1 slots; c (B,2,H) -> f32 buffers
__global__ void init_states_kernel(const float* __restrict__ h_in,
                                   const float* __restrict__ c_in,
                                   unsigned short* __restrict__ h0buf,
                                   unsigned short* __restrict__ h1buf,
                                   float* __restrict__ c0, float* __restrict__ c1) {
  int i = blockIdx.x * blockDim.x + threadIdx.x;  // 0 .. 256*512-1
  if (i >= BB * HH) return;
  int b = i >> 9, j = i & 511;
  h0buf[BB * HH + i] = f2bf(h_in[(b * 2 + 0) * HH + j]);
  h1buf[BB * HH + i] = f2bf(h_in[(b * 2 + 1) * HH + j]);
  c0[i] = c_in[(b * 2 + 0) * HH + j];
  c1[i] = c_in[(b * 2 + 1) * HH + j];
}

// ---------------- phase 1 (modes 0/1): xg = x @ W_ih0^T + bias0, time-major ----
// M=32768 (m=b*T+t), K=256, N=2048.  Split-A (hi+lo bf16) to kill x-rounding.
template<bool XGF32>
__global__ __launch_bounds__(256) void xgemm_kernel(
    const float* __restrict__ x,     // (32768,256)
    const float* __restrict__ wih0,  // (2048,256)
    const float* __restrict__ b_ih0,
    const float* __restrict__ b_hh0,
    void* __restrict__ xg)           // [t][b][2048]
{
  int bid = blockIdx.x;
  int mt = bid >> 4, nt = bid & 15;
  int wv = threadIdx.x >> 6, lane = threadIdx.x & 63;
  int wr = wv >> 1, wc = wv & 1;
  int row0 = mt * 128 + wr * 64;
  int col0 = nt * 128 + wc * 64;
  int lr = lane & 15, lkb = (lane >> 4) << 3;

  f32x4 acc[4][4] = {};
  for (int kk = 0; kk < II; kk += 32) {
    bf16x8 ah[4], al[4], bh[4];
#pragma unroll
    for (int mi = 0; mi < 4; ++mi) {
      const float* p = &x[(size_t)(row0 + mi * 16 + lr) * II + kk + lkb];
      float4 v0 = *(const float4*)p;
      float4 v1 = *(const float4*)(p + 4);
      float vv[8] = {v0.x, v0.y, v0.z, v0.w, v1.x, v1.y, v1.z, v1.w};
#pragma unroll
      for (int j = 0; j < 8; ++j) {
        unsigned short hi = f2bf(vv[j]);
        ah[mi][j] = (short)hi;
        al[mi][j] = (short)f2bf(vv[j] - bf2f(hi));
      }
    }
#pragma unroll
    for (int ni = 0; ni < 4; ++ni) {
      const float* p = &wih0[(size_t)(col0 + ni * 16 + lr) * II + kk + lkb];
      float4 v0 = *(const float4*)p;
      float4 v1 = *(const float4*)(p + 4);
      float vv[8] = {v0.x, v0.y, v0.z, v0.w, v1.x, v1.y, v1.z, v1.w};
#pragma unroll
      for (int j = 0; j < 8; ++j) bh[ni][j] = (short)f2bf(vv[j]);
    }
#pragma unroll
    for (int mi = 0; mi < 4; ++mi)
#pragma unroll
      for (int ni = 0; ni < 4; ++ni) {
        acc[mi][ni] = __builtin_amdgcn_mfma_f32_16x16x32_bf16(ah[mi], bh[ni], acc[mi][ni], 0, 0, 0);
        acc[mi][ni] = __builtin_amdgcn_mfma_f32_16x16x32_bf16(al[mi], bh[ni], acc[mi][ni], 0, 0, 0);
      }
  }
  int orow = (lane >> 4) << 2, ocol = lane & 15;
#pragma unroll
  for (int ni = 0; ni < 4; ++ni) {
    int n = col0 + ni * 16 + ocol;
    float bias = b_ih0[n] + b_hh0[n];
#pragma unroll
    for (int mi = 0; mi < 4; ++mi) {
#pragma unroll
      for (int r = 0; r < 4; ++r) {
        int m = row0 + mi * 16 + orow + r;
        int t = m & 127, b = m >> 7;
        size_t idx = ((size_t)t * BB + b) * GG + n;
        float v = acc[mi][ni][r] + bias;
        if (XGF32) ((float*)xg)[idx] = v;
        else ((unsigned short*)xg)[idx] = f2bf(v);
      }
    }
  }
}

// ---------------- phase 2: one regular launch per pipeline phase -------------
// grid = 128 blocks x 256 threads.
//  blocks  0..63 : layer0, t = p      (skip if p >= 128). 32 rows x 64 hid cols.
//  blocks 64..127: layer1, t = p - 1  (skip if p < 1).    32 rows x 64 hid cols.
// h-state slot parity for timestep t is (t & 1); initial states live in parity 1.
// XMODE: 0 = f32 xg precomputed, 1 = bf16 xg precomputed, 2 = recompute x-GEMM.
template<int XMODE>
__global__ __launch_bounds__(256) void phase_kernel(
    int p,
    const void* __restrict__ xgx,              // xg (0/1) or x (2)
    const unsigned short* __restrict__ wih0bf, // (2048,256) bf16  (mode 2)
    const float* __restrict__ bias0,           // 2048             (mode 2)
    const unsigned short* __restrict__ whh0,   // (2048,512) bf16
    const unsigned short* __restrict__ w1cat,  // (2048,1024) bf16
    const float* __restrict__ bias1,           // 2048
    unsigned short* __restrict__ h0buf,        // [2][256][512] bf16
    unsigned short* __restrict__ h1buf,        // [2][256][512] bf16
    float* __restrict__ c0, float* __restrict__ c1,
    const unsigned char* __restrict__ mask,    // [256][128]
    float* __restrict__ out)
{
  const int bid = blockIdx.x;
  const int wv = threadIdx.x >> 6, lane = threadIdx.x & 63;
  const int lr = lane & 15, lkb = (lane >> 4) << 3;
  const int orow = (lane >> 4) << 2, ocol = lane & 15;
  const bf16x8 az = {0, 0, 0, 0, 0, 0, 0, 0};

  if (bid < 64) {
    // ---------------- layer 0, t = p ----------------
    if (p >= TT) return;
    const int t = p;
    const int rm0 = (bid >> 3) * 32;
    const int jb = (bid & 7) * 64 + wv * 16;
    const unsigned short* hprev = h0buf + ((t + 1) & 1) * (BB * HH);  // h0(t-1)
    f32x4 acc[4][2] = {};  // [gate][mi]
    bool mz[2];
#pragma unroll
    for (int mi = 0; mi < 2; ++mi) mz[mi] = mask[(rm0 + mi * 16 + lr) * TT + t] != 0;

    if (XMODE == 2) {
      const float* x = (const float*)xgx;  // (B,T,I)
      for (int kk = 0; kk < II; kk += 32) {
        bf16x8 a[2], b[4];
#pragma unroll
        for (int mi = 0; mi < 2; ++mi) {
          const float* px = &x[((size_t)(rm0 + mi * 16 + lr) * TT + t) * II + kk + lkb];
          float4 v0 = *(const float4*)px;
          float4 v1 = *(const float4*)(px + 4);
          float vv[8] = {v0.x, v0.y, v0.z, v0.w, v1.x, v1.y, v1.z, v1.w};
#pragma unroll
          for (int j = 0; j < 8; ++j) a[mi][j] = (short)f2bf(vv[j]);
        }
#pragma unroll
        for (int q = 0; q < 4; ++q)
          b[q] = *(const bf16x8*)&wih0bf[(size_t)(q * 512 + jb + lr) * II + kk + lkb];
#pragma unroll
        for (int q = 0; q < 4; ++q)
#pragma unroll
          for (int mi = 0; mi < 2; ++mi)
            acc[q][mi] = __builtin_amdgcn_mfma_f32_16x16x32_bf16(a[mi], b[q], acc[q][mi], 0, 0, 0);
      }
    }
    for (int kk = 0; kk < HH; kk += 32) {
      bf16x8 a[2], b[4];
#pragma unroll
      for (int mi = 0; mi < 2; ++mi) {
        bf16x8 v = *(const bf16x8*)&hprev[(size_t)(rm0 + mi * 16 + lr) * HH + kk + lkb];
        if (mz[mi]) v = az;
        a[mi] = v;
      }
#pragma unroll
      for (int q = 0; q < 4; ++q)
        b[q] = *(const bf16x8*)&whh0[(size_t)(q * 512 + jb + lr) * HH + kk + lkb];
#pragma unroll
      for (int q = 0; q < 4; ++q)
#pragma unroll
        for (int mi = 0; mi < 2; ++mi)
          acc[q][mi] = __builtin_amdgcn_mfma_f32_16x16x32_bf16(a[mi], b[q], acc[q][mi], 0, 0, 0);
    }
    unsigned short* hcur = h0buf + (t & 1) * (BB * HH);
#pragma unroll
    for (int mi = 0; mi < 2; ++mi) {
#pragma unroll
      for (int r = 0; r < 4; ++r) {
        int row = rm0 + mi * 16 + orow + r;
        int j = jb + ocol;
        float g0, g1, g2, g3;
        if (XMODE == 0) {
          const float* xp = (const float*)xgx + ((size_t)t * BB + row) * GG;
          g0 = xp[j]; g1 = xp[512 + j]; g2 = xp[1024 + j]; g3 = xp[1536 + j];
        } else if (XMODE == 1) {
          const unsigned short* xp = (const unsigned short*)xgx + ((size_t)t * BB + row) * GG;
          g0 = bf2f(xp[j]); g1 = bf2f(xp[512 + j]); g2 = bf2f(xp[1024 + j]); g3 = bf2f(xp[1536 + j]);
        } else {
          g0 = bias0[j]; g1 = bias0[512 + j]; g2 = bias0[1024 + j]; g3 = bias0[1536 + j];
        }
        g0 += acc[0][mi][r]; g1 += acc[1][mi][r]; g2 += acc[2][mi][r]; g3 += acc[3][mi][r];
        float cp = mask[row * TT + t] ? 0.0f : c0[row * HH + j];
        float ig = sigm(g0), fg = sigm(g1), gg = tanhf(g2), og = sigm(g3);
        float cn = fg * cp + ig * gg;
        float hn = og * tanhf(cn);
        c0[row * HH + j] = cn;
        hcur[row * HH + j] = f2bf(hn);
        if (t == TT - 1) {
          out[OUT_HN + (row * 2 + 0) * HH + j] = hn;
          out[OUT_CN + (row * 2 + 0) * HH + j] = cn;
        }
      }
    }
  } else {
    // ---------------- layer 1, t = p - 1 ----------------
    if (p < 1) return;
    const int t = p - 1;
    const int lb = bid - 64;
    const int rm0 = (lb >> 3) * 32;
    const int jb = (lb & 7) * 64 + wv * 16;
    const unsigned short* h0cur  = h0buf + (t & 1) * (BB * HH);        // h0(t)
    const unsigned short* h1prev = h1buf + ((t + 1) & 1) * (BB * HH);  // h1(t-1)
    f32x4 acc[4][2] = {};
    bool mz[2];
#pragma unroll
    for (int mi = 0; mi < 2; ++mi) mz[mi] = mask[(rm0 + mi * 16 + lr) * TT + t] != 0;
    for (int kk = 0; kk < 1024; kk += 32) {
      bf16x8 a[2], b[4];
      if (kk < 512) {
#pragma unroll
        for (int mi = 0; mi < 2; ++mi)
          a[mi] = *(const bf16x8*)&h0cur[(size_t)(rm0 + mi * 16 + lr) * HH + kk + lkb];
      } else {
#pragma unroll
        for (int mi = 0; mi < 2; ++mi) {
          bf16x8 v = *(const bf16x8*)&h1prev[(size_t)(rm0 + mi * 16 + lr) * HH + (kk - 512) + lkb];
          if (mz[mi]) v = az;
          a[mi] = v;
        }
      }
#pragma unroll
      for (int q = 0; q < 4; ++q)
        b[q] = *(const bf16x8*)&w1cat[(size_t)(q * 512 + jb + lr) * 1024 + kk + lkb];
#pragma unroll
      for (int q = 0; q < 4; ++q)
#pragma unroll
        for (int mi = 0; mi < 2; ++mi)
          acc[q][mi] = __builtin_amdgcn_mfma_f32_16x16x32_bf16(a[mi], b[q], acc[q][mi], 0, 0, 0);
    }
    unsigned short* h1cur = h1buf + (t & 1) * (BB * HH);
#pragma unroll
    for (int mi = 0; mi < 2; ++mi) {
#pragma unroll
      for (int r = 0; r < 4; ++r) {
        int row = rm0 + mi * 16 + orow + r;
        int j = jb + ocol;
        float g0 = acc[0][mi][r] + bias1[j];
        float g1 = acc[1][mi][r] + bias1[512 + j];
        float g2 = acc[2][mi][r] + bias1[1024 + j];
        float g3 = acc[3][mi][r] + bias1[1536 + j];
        float cp = mask[row * TT + t] ? 0.0f : c1[row * HH + j];
        float ig = sigm(g0), fg = sigm(g1), gg = tanhf(g2), og = sigm(g3);
        float cn = fg * cp + ig * gg;
        float hn = og * tanhf(cn);
        c1[row * HH + j] = cn;
        h1cur[row * HH + j] = f2bf(hn);
        out[(size_t)row * (TT * HH) + (size_t)t * HH + j] = hn;
        if (t == TT - 1) {
          out[OUT_HN + (row * 2 + 1) * HH + j] = hn;
          out[OUT_CN + (row * 2 + 1) * HH + j] = cn;
        }
      }
    }
  }
}

// ---------------- host ----------------

extern "C" void kernel_launch(void* const* d_in, const int* in_sizes, int n_in,
                              void* d_out, int out_size, void* d_ws, size_t ws_size,
                              hipStream_t stream) {
  const float* x     = (const float*)d_in[0];
  const void*  isini = d_in[1];
  const float* h_in  = (const float*)d_in[2];
  const float* c_in  = (const float*)d_in[3];
  const float* wih0  = (const float*)d_in[4];
  const float* whh0f = (const float*)d_in[5];
  const float* bih0  = (const float*)d_in[6];
  const float* bhh0  = (const float*)d_in[7];
  const float* wih1  = (const float*)d_in[8];
  const float* whh1f = (const float*)d_in[9];
  const float* bih1  = (const float*)d_in[10];
  const float* bhh1  = (const float*)d_in[11];
  float* out = (float*)d_out;

  char* ws = (char*)d_ws;
  size_t off = 0;
  auto alloc = [&](size_t bytes) -> char* {
    char* p = ws + off;
    off = (off + bytes + 255) & ~(size_t)255;
    return p;
  };
  unsigned short* whh0_bf = (unsigned short*)alloc((size_t)GG * 512 * 2);
  unsigned short* w1cat   = (unsigned short*)alloc((size_t)GG * 1024 * 2);
  unsigned short* wih0_bf = (unsigned short*)alloc((size_t)GG * 256 * 2);
  float*          bias0   = (float*)alloc((size_t)GG * 4);
  float*          bias1   = (float*)alloc((size_t)GG * 4);
  unsigned short* h0buf   = (unsigned short*)alloc((size_t)2 * BB * HH * 2);
  unsigned short* h1buf   = (unsigned short*)alloc((size_t)2 * BB * HH * 2);
  float*          c0      = (float*)alloc((size_t)BB * HH * 4);
  float*          c1      = (float*)alloc((size_t)BB * HH * 4);
  unsigned char*  mask    = (unsigned char*)alloc((size_t)BB * TT);
  int*            flag    = (int*)alloc(256);
  size_t fixed = off;
  size_t xg_elems = (size_t)TT * BB * GG;  // 67,108,864
  int xmode;
  if (ws_size >= fixed + xg_elems * 4)      xmode = 0;
  else if (ws_size >= fixed + xg_elems * 2) xmode = 1;
  else                                      xmode = 2;
  void* xg = (void*)alloc(xmode == 0 ? xg_elems * 4 : (xmode == 1 ? xg_elems * 2 : 0));

  detect_init_kernel<<<1, 256, 0, stream>>>((const unsigned int*)isini, (BB * TT) / 4, flag);
  expand_mask_kernel<<<(BB * TT) / 256, 256, 0, stream>>>(isini, flag, mask, BB * TT);
  conv_bf16_kernel<<<512, 256, 0, stream>>>(whh0f, whh0_bf, GG * 512);
  conv_bf16_kernel<<<256, 256, 0, stream>>>(wih0, wih0_bf, GG * 256);
  build_w1cat_kernel<<<512, 256, 0, stream>>>(wih1, whh1f, w1cat);
  build_bias_kernel<<<8, 256, 0, stream>>>(bih0, bhh0, bias0);
  build_bias_kernel<<<8, 256, 0, stream>>>(bih1, bhh1, bias1);
  init_states_kernel<<<(BB * HH) / 256, 256, 0, stream>>>(h_in, c_in, h0buf, h1buf, c0, c1);

  const void* xgx = xg;
  if (xmode == 0) {
    xgemm_kernel<true><<<4096, 256, 0, stream>>>(x, wih0, bih0, bhh0, xg);
  } else if (xmode == 1) {
    xgemm_kernel<false><<<4096, 256, 0, stream>>>(x, wih0, bih0, bhh0, xg);
  } else {
    xgx = (const void*)x;
  }

  for (int p = 0; p <= TT; ++p) {
    if (xmode == 0)
      phase_kernel<0><<<128, 256, 0, stream>>>(p, xgx, wih0_bf, bias0, whh0_bf, w1cat,
                                               bias1, h0buf, h1buf, c0, c1, mask, out);
    else if (xmode == 1)
      phase_kernel<1><<<128, 256, 0, stream>>>(p, xgx, wih0_bf, bias0, whh0_bf, w1cat,
                                               bias1, h0buf, h1buf, c0, c1, mask, out);
    else
      phase_kernel<2><<<128, 256, 0, stream>>>(p, xgx, wih0_bf, bias0, whh0_bf, w1cat,
                                               bias1, h0buf, h1buf, c0, c1, mask, out);
  }
}